// Round 1
// baseline (325.619 us; speedup 1.0000x reference)
//
#include <hip/hip_runtime.h>
#include <math.h>

#define L_TOK 16
#define DMODEL 1024
#define NHEAD 16
#define DHEAD 64
#define NBLK 1024
#define BSZ 16
#define START_POS_C 16368
#define TTOT 16384
#define SPLITS 128
#define CHUNK 128          // tokens per split (8 tiles of 16)
#define KSPLIT 8
#define QSCALE (0.125f * 1.4426950408889634f)   // 1/sqrt(64) * log2(e)

// workspace offsets, in floats
#define OFF_QKVP 0                                        // 8*16*3072 = 393216
#define OFF_QW   (OFF_QKVP + KSPLIT * L_TOK * 3 * DMODEL) // 393216
#define OFF_ACC  (OFF_QW + NHEAD * L_TOK * DHEAD)         // 409600
#define OFF_ML   (OFF_ACC + NHEAD * SPLITS * L_TOK * DHEAD) // 2506752
#define OFF_ATTN (OFF_ML + NHEAD * SPLITS * L_TOK * 2)    // 2572288
#define OFF_PROJP (OFF_ATTN + L_TOK * DMODEL)             // 2588672
// end = 2719744 floats = ~10.4 MB of ws

// ---------------------------------------------------------------------------
// Split-K partial GEMM: out[l][n] partials over K chunks of 128.
// grid = (ncols/64, KSPLIT), block = 256 (4 waves; wave w handles rows 4w..4w+3)
// ---------------------------------------------------------------------------
__global__ __launch_bounds__(256) void gemm_part(const float* __restrict__ x,
                                                 const float* __restrict__ W,
                                                 float* __restrict__ part,
                                                 int ncols) {
    const int lane = threadIdx.x & 63;
    const int wv = threadIdx.x >> 6;
    const int n = blockIdx.x * 64 + lane;
    const int k0 = blockIdx.y * (DMODEL / KSPLIT);
    const float* xr = x + (size_t)(wv * 4) * DMODEL;
    float a0 = 0.f, a1 = 0.f, a2 = 0.f, a3 = 0.f;
#pragma unroll 4
    for (int k = k0; k < k0 + DMODEL / KSPLIT; ++k) {
        float w = W[(size_t)k * ncols + n];
        a0 = fmaf(xr[k], w, a0);
        a1 = fmaf(xr[DMODEL + k], w, a1);
        a2 = fmaf(xr[2 * DMODEL + k], w, a2);
        a3 = fmaf(xr[3 * DMODEL + k], w, a3);
    }
    size_t base = ((size_t)blockIdx.y * L_TOK + wv * 4) * ncols + n;
    part[base] = a0;
    part[base + (size_t)ncols] = a1;
    part[base + 2 * (size_t)ncols] = a2;
    part[base + 3 * (size_t)ncols] = a3;
}

// ---------------------------------------------------------------------------
// Reduce split-K partials of QKV, add bias, scatter:
//   q (scaled by SCALE*log2e) -> q_ws[h][l][d]
//   k,v of the 16 new tokens  -> written into the pools (paged)
// grid = 192 x 256  (49152 outputs)
// ---------------------------------------------------------------------------
__global__ __launch_bounds__(256) void qkv_reduce_scatter(const float* __restrict__ part,
                                                          const float* __restrict__ b_attn,
                                                          const int* __restrict__ block_ids,
                                                          float* __restrict__ qws,
                                                          float* __restrict__ kpool,
                                                          float* __restrict__ vpool) {
    int tid = blockIdx.x * 256 + threadIdx.x;
    int n = tid % (3 * DMODEL);
    int l = tid / (3 * DMODEL);
    float s = b_attn[n];
#pragma unroll
    for (int kb = 0; kb < KSPLIT; ++kb)
        s += part[((size_t)kb * L_TOK + l) * (3 * DMODEL) + n];
    int sec = n >> 10;
    int m = n & (DMODEL - 1);
    int h = m >> 6;
    int dd = m & 63;
    if (sec == 0) {
        qws[(h * L_TOK + l) * DHEAD + dd] = s * QSCALE;
    } else {
        int pos = START_POS_C + l;
        int blk = block_ids[pos >> 4];
        int off = pos & 15;
        size_t idx = (((size_t)blk * BSZ + off) * NHEAD + h) * DHEAD + dd;
        if (sec == 1) kpool[idx] = s;
        else          vpool[idx] = s;
    }
}

// ---------------------------------------------------------------------------
// Flash-decode paged attention. grid = (NHEAD, SPLITS), block = 64 (1 wave).
// lane = tg*16 + l : tg in [0,4) owns 4 tokens (QK) / 16 dims (PV), l = query.
// Writes unnormalized acc + (m, sumexp) per (h, split, l) to ws.
// ---------------------------------------------------------------------------
__global__ __launch_bounds__(64) void paged_attn(const float* __restrict__ kpool,
                                                 const float* __restrict__ vpool,
                                                 const int* __restrict__ block_ids,
                                                 const float* __restrict__ qws,
                                                 float* __restrict__ accws,
                                                 float* __restrict__ mlws) {
    const int h = blockIdx.x;
    const int s = blockIdx.y;
    const int lane = threadIdx.x;
    const int tg = lane >> 4;
    const int l = lane & 15;

    __shared__ float4 k_lds[16][17];   // 16 tokens x 64 f32, padded (17 float4)
    __shared__ float4 v_lds[16][17];
    __shared__ float4 p_lds[16][5];    // p[l][t] as 4 float4, padded stride 5

    float4 q[16];
    {
        const float4* qp = (const float4*)(qws + (size_t)(h * L_TOK + l) * DHEAD);
#pragma unroll
        for (int c = 0; c < 16; ++c) q[c] = qp[c];
    }
    float acc[16];
#pragma unroll
    for (int j = 0; j < 16; ++j) acc[j] = 0.f;
    float m_run = -INFINITY, se_run = 0.f;

    const int t0 = s * CHUNK;
    for (int tile = 0; tile < CHUNK / 16; ++tile) {
        const int tbase = t0 + tile * 16;
        const int pb = block_ids[tbase >> 4];
        const float* kb = kpool + ((size_t)pb * BSZ * NHEAD + h) * DHEAD;
        const float* vb = vpool + ((size_t)pb * BSZ * NHEAD + h) * DHEAD;
        // stage K,V tile: 16 rows x 256B each, coalesced float4
#pragma unroll
        for (int j = 0; j < 4; ++j) {
            int idx = j * 64 + lane;
            int row = idx >> 4, c = idx & 15;
            k_lds[row][c] = ((const float4*)(kb + (size_t)row * (NHEAD * DHEAD)))[c];
        }
#pragma unroll
        for (int j = 0; j < 4; ++j) {
            int idx = j * 64 + lane;
            int row = idx >> 4, c = idx & 15;
            v_lds[row][c] = ((const float4*)(vb + (size_t)row * (NHEAD * DHEAD)))[c];
        }
        __syncthreads();

        // QK: each lane computes full 64-dim dots for its 4 tokens
        float s4[4];
#pragma unroll
        for (int i = 0; i < 4; ++i) {
            const int tok = tg * 4 + i;
            float d0 = 0.f, d1 = 0.f;
#pragma unroll
            for (int c = 0; c < 16; c += 2) {
                float4 kv0 = k_lds[tok][c];
                float4 kv1 = k_lds[tok][c + 1];
                float4 q0 = q[c], q1 = q[c + 1];
                d0 = fmaf(q0.x, kv0.x, d0); d0 = fmaf(q0.y, kv0.y, d0);
                d0 = fmaf(q0.z, kv0.z, d0); d0 = fmaf(q0.w, kv0.w, d0);
                d1 = fmaf(q1.x, kv1.x, d1); d1 = fmaf(q1.y, kv1.y, d1);
                d1 = fmaf(q1.z, kv1.z, d1); d1 = fmaf(q1.w, kv1.w, d1);
            }
            s4[i] = d0 + d1;
        }
        // causal mask: only the final tile (tbase == START_POS) is affected
        if (tbase + 15 > START_POS_C) {
#pragma unroll
            for (int i = 0; i < 4; ++i) {
                int tglob = tbase + tg * 4 + i;
                if (tglob > START_POS_C + l) s4[i] = -INFINITY;
            }
        }
        // online softmax (log2 domain; scale folded into q)
        float tmax = fmaxf(fmaxf(s4[0], s4[1]), fmaxf(s4[2], s4[3]));
        tmax = fmaxf(tmax, __shfl_xor(tmax, 16, 64));
        tmax = fmaxf(tmax, __shfl_xor(tmax, 32, 64));
        const float m_new = fmaxf(m_run, tmax);
        const float alpha = exp2f(m_run - m_new);
        float4 p4;
        p4.x = exp2f(s4[0] - m_new);
        p4.y = exp2f(s4[1] - m_new);
        p4.z = exp2f(s4[2] - m_new);
        p4.w = exp2f(s4[3] - m_new);
        float tsum = (p4.x + p4.y) + (p4.z + p4.w);
        tsum += __shfl_xor(tsum, 16, 64);
        tsum += __shfl_xor(tsum, 32, 64);
        se_run = se_run * alpha + tsum;
        m_run = m_new;
#pragma unroll
        for (int j = 0; j < 16; ++j) acc[j] *= alpha;
        p_lds[l][tg] = p4;
        __syncthreads();

        // PV: lane accumulates dims [tg*16, tg*16+16) over all 16 tokens
#pragma unroll
        for (int c = 0; c < 4; ++c) {
            float4 pc = p_lds[l][c];
#pragma unroll
            for (int i = 0; i < 4; ++i) {
                const int tok = c * 4 + i;
                const float pv = (i == 0) ? pc.x : ((i == 1) ? pc.y : ((i == 2) ? pc.z : pc.w));
                float4 v0 = v_lds[tok][tg * 4 + 0];
                float4 v1 = v_lds[tok][tg * 4 + 1];
                float4 v2 = v_lds[tok][tg * 4 + 2];
                float4 v3 = v_lds[tok][tg * 4 + 3];
                acc[0]  = fmaf(pv, v0.x, acc[0]);  acc[1]  = fmaf(pv, v0.y, acc[1]);
                acc[2]  = fmaf(pv, v0.z, acc[2]);  acc[3]  = fmaf(pv, v0.w, acc[3]);
                acc[4]  = fmaf(pv, v1.x, acc[4]);  acc[5]  = fmaf(pv, v1.y, acc[5]);
                acc[6]  = fmaf(pv, v1.z, acc[6]);  acc[7]  = fmaf(pv, v1.w, acc[7]);
                acc[8]  = fmaf(pv, v2.x, acc[8]);  acc[9]  = fmaf(pv, v2.y, acc[9]);
                acc[10] = fmaf(pv, v2.z, acc[10]); acc[11] = fmaf(pv, v2.w, acc[11]);
                acc[12] = fmaf(pv, v3.x, acc[12]); acc[13] = fmaf(pv, v3.y, acc[13]);
                acc[14] = fmaf(pv, v3.z, acc[14]); acc[15] = fmaf(pv, v3.w, acc[15]);
            }
        }
        __syncthreads();   // protect LDS buffers before next tile's staging
    }

    size_t obase = (((size_t)h * SPLITS + s) * L_TOK + l) * DHEAD + tg * 16;
    float4* op = (float4*)(accws + obase);
    op[0] = make_float4(acc[0], acc[1], acc[2], acc[3]);
    op[1] = make_float4(acc[4], acc[5], acc[6], acc[7]);
    op[2] = make_float4(acc[8], acc[9], acc[10], acc[11]);
    op[3] = make_float4(acc[12], acc[13], acc[14], acc[15]);
    if (tg == 0) {
        size_t mb = (((size_t)h * SPLITS + s) * L_TOK + l) * 2;
        mlws[mb] = m_run;
        mlws[mb + 1] = se_run;
    }
}

// ---------------------------------------------------------------------------
// Combine split partials -> attn_ws[l][h*64+d]. grid = H*L blocks x 64.
// ---------------------------------------------------------------------------
__global__ __launch_bounds__(64) void combine(const float* __restrict__ accws,
                                              const float* __restrict__ mlws,
                                              float* __restrict__ attnws) {
    const int h = blockIdx.x >> 4;
    const int l = blockIdx.x & 15;
    const int lane = threadIdx.x;
    float M = -INFINITY;
    for (int s = 0; s < SPLITS; ++s)
        M = fmaxf(M, mlws[(((size_t)h * SPLITS + s) * L_TOK + l) * 2]);
    float num = 0.f, den = 0.f;
    for (int s = 0; s < SPLITS; ++s) {
        size_t mb = (((size_t)h * SPLITS + s) * L_TOK + l) * 2;
        float w = exp2f(mlws[mb] - M);
        den = fmaf(w, mlws[mb + 1], den);
        num = fmaf(w, accws[(((size_t)h * SPLITS + s) * L_TOK + l) * DHEAD + lane], num);
    }
    attnws[(size_t)l * DMODEL + h * DHEAD + lane] = num / den;
}

// ---------------------------------------------------------------------------
// Reduce split-K partials of final projection + bias -> d_out. grid 64x256.
// ---------------------------------------------------------------------------
__global__ __launch_bounds__(256) void proj_reduce(const float* __restrict__ part,
                                                   const float* __restrict__ bias,
                                                   float* __restrict__ out) {
    int tid = blockIdx.x * 256 + threadIdx.x;   // < 16384
    int n = tid & (DMODEL - 1);
    int l = tid >> 10;
    float s = bias[n];
#pragma unroll
    for (int kb = 0; kb < KSPLIT; ++kb)
        s += part[((size_t)kb * L_TOK + l) * DMODEL + n];
    out[tid] = s;
}

extern "C" void kernel_launch(void* const* d_in, const int* in_sizes, int n_in,
                              void* d_out, int out_size, void* d_ws, size_t ws_size,
                              hipStream_t stream) {
    const float* x       = (const float*)d_in[0];
    float* kpool         = (float*)d_in[1];
    float* vpool         = (float*)d_in[2];
    const float* W_attn  = (const float*)d_in[3];
    const float* b_attn  = (const float*)d_in[4];
    const float* W_proj  = (const float*)d_in[5];
    const float* b_proj  = (const float*)d_in[6];
    const int* block_ids = (const int*)d_in[7];
    float* ws  = (float*)d_ws;
    float* out = (float*)d_out;

    // 1) QKV projection (split-K partials)
    gemm_part<<<dim3(48, KSPLIT), 256, 0, stream>>>(x, W_attn, ws + OFF_QKVP, 3 * DMODEL);
    // 2) reduce + bias; q -> ws (scaled), new k/v -> pools (paged write)
    qkv_reduce_scatter<<<192, 256, 0, stream>>>(ws + OFF_QKVP, b_attn, block_ids,
                                                ws + OFF_QW, kpool, vpool);
    // 3) flash-decode attention over the full prefix
    paged_attn<<<dim3(NHEAD, SPLITS), 64, 0, stream>>>(kpool, vpool, block_ids,
                                                       ws + OFF_QW, ws + OFF_ACC, ws + OFF_ML);
    // 4) combine splits
    combine<<<NHEAD * L_TOK, 64, 0, stream>>>(ws + OFF_ACC, ws + OFF_ML, ws + OFF_ATTN);
    // 5) output projection (split-K partials)
    gemm_part<<<dim3(16, KSPLIT), 256, 0, stream>>>(ws + OFF_ATTN, W_proj, ws + OFF_PROJP, DMODEL);
    // 6) reduce + bias -> d_out
    proj_reduce<<<64, 256, 0, stream>>>(ws + OFF_PROJP, b_proj, out);
}

// Round 2
// 231.564 us; speedup vs baseline: 1.4062x; 1.4062x over previous
//
#include <hip/hip_runtime.h>
#include <math.h>

#define L_TOK 16
#define DMODEL 1024
#define NHEAD 16
#define DHEAD 64
#define NBLK 1024
#define BSZ 16
#define START_POS_C 16368
#define TTOT 16384
#define SPLITS 128
#define CHUNK 128          // tokens per split (8 tiles of 16)
#define KSPLIT 16
#define QSCALE (0.125f * 1.4426950408889634f)   // 1/sqrt(64) * log2(e)

// workspace offsets, in floats
#define OFF_QKVP 0                                          // 16*16*3072 = 786432
#define OFF_QW   (OFF_QKVP + KSPLIT * L_TOK * 3 * DMODEL)   // 786432
#define OFF_ACC  (OFF_QW + NHEAD * L_TOK * DHEAD)           // 802816
#define OFF_M    (OFF_ACC + NHEAD * SPLITS * L_TOK * DHEAD) // 2899968
#define OFF_SE   (OFF_M + NHEAD * SPLITS * L_TOK)           // 2932736
#define OFF_ATTN (OFF_SE + NHEAD * SPLITS * L_TOK)          // 2965504
#define OFF_PROJP (OFF_ATTN + L_TOK * DMODEL)               // 2981888
// end = 3244032 floats = 12.4 MB

// ---------------------------------------------------------------------------
// DPP helpers: row_ror:R rotates values within each 16-lane row. Direction
// does not matter for correctness: the token index travels through the SAME
// permutation (dppror_i on the lane-id vector), so QK, mask, and PV stay
// consistent for any rotation convention.
// ---------------------------------------------------------------------------
template<int R>
__device__ __forceinline__ float dppror(float x) {
    if constexpr (R == 0) {
        return x;
    } else {
        int i = __builtin_amdgcn_update_dpp(0, __float_as_int(x), 0x120 + R, 0xF, 0xF, false);
        return __int_as_float(i);
    }
}
template<int R>
__device__ __forceinline__ int dppror_i(int x) {
    if constexpr (R == 0) return x;
    else return __builtin_amdgcn_update_dpp(0, x, 0x120 + R, 0xF, 0xF, false);
}

template<int R>
__device__ __forceinline__ float qk_step(const float* ql, const float* kk) {
    float d0 = 0.f, d1 = 0.f, d2 = 0.f, d3 = 0.f;
#pragma unroll
    for (int c = 0; c < 4; ++c) {
        d0 = fmaf(ql[c],      dppror<R>(kk[c]),      d0);
        d1 = fmaf(ql[4 + c],  dppror<R>(kk[4 + c]),  d1);
        d2 = fmaf(ql[8 + c],  dppror<R>(kk[8 + c]),  d2);
        d3 = fmaf(ql[12 + c], dppror<R>(kk[12 + c]), d3);
    }
    return (d0 + d1) + (d2 + d3);
}

template<int R>
__device__ __forceinline__ void pv_step(float p, const float* vv, float* acc) {
#pragma unroll
    for (int c = 0; c < 16; ++c)
        acc[c] = fmaf(p, dppror<R>(vv[c]), acc[c]);
}

// ---------------------------------------------------------------------------
// Split-K partial GEMM: out[l][n] partials over K chunks of 64.
// grid = (ncols/64, KSPLIT), block = 256 (4 waves; wave w handles rows 4w..4w+3)
// ---------------------------------------------------------------------------
__global__ __launch_bounds__(256) void gemm_part(const float* __restrict__ x,
                                                 const float* __restrict__ W,
                                                 float* __restrict__ part,
                                                 int ncols) {
    const int lane = threadIdx.x & 63;
    const int wv = threadIdx.x >> 6;
    const int n = blockIdx.x * 64 + lane;
    const int k0 = blockIdx.y * (DMODEL / KSPLIT);
    const float* xr = x + (size_t)(wv * 4) * DMODEL;
    float a0 = 0.f, a1 = 0.f, a2 = 0.f, a3 = 0.f;
#pragma unroll 8
    for (int k = k0; k < k0 + DMODEL / KSPLIT; ++k) {
        float w = W[(size_t)k * ncols + n];
        a0 = fmaf(xr[k], w, a0);
        a1 = fmaf(xr[DMODEL + k], w, a1);
        a2 = fmaf(xr[2 * DMODEL + k], w, a2);
        a3 = fmaf(xr[3 * DMODEL + k], w, a3);
    }
    size_t base = ((size_t)blockIdx.y * L_TOK + wv * 4) * ncols + n;
    part[base] = a0;
    part[base + (size_t)ncols] = a1;
    part[base + 2 * (size_t)ncols] = a2;
    part[base + 3 * (size_t)ncols] = a3;
}

// ---------------------------------------------------------------------------
// Reduce split-K partials of QKV, add bias, scatter:
//   q (scaled by SCALE*log2e) -> q_ws[h][l][d]
//   k,v of the 16 new tokens  -> written into the pools (paged)
// ---------------------------------------------------------------------------
__global__ __launch_bounds__(256) void qkv_reduce_scatter(const float* __restrict__ part,
                                                          const float* __restrict__ b_attn,
                                                          const int* __restrict__ block_ids,
                                                          float* __restrict__ qws,
                                                          float* __restrict__ kpool,
                                                          float* __restrict__ vpool) {
    int tid = blockIdx.x * 256 + threadIdx.x;
    int n = tid % (3 * DMODEL);
    int l = tid / (3 * DMODEL);
    float s = b_attn[n];
#pragma unroll
    for (int kb = 0; kb < KSPLIT; ++kb)
        s += part[((size_t)kb * L_TOK + l) * (3 * DMODEL) + n];
    int sec = n >> 10;
    int m = n & (DMODEL - 1);
    int h = m >> 6;
    int dd = m & 63;
    if (sec == 0) {
        qws[(h * L_TOK + l) * DHEAD + dd] = s * QSCALE;
    } else {
        int pos = START_POS_C + l;
        int blk = block_ids[pos >> 4];
        int off = pos & 15;
        size_t idx = (((size_t)blk * BSZ + off) * NHEAD + h) * DHEAD + dd;
        if (sec == 1) kpool[idx] = s;
        else          vpool[idx] = s;
    }
}

// ---------------------------------------------------------------------------
// Flash-decode paged attention, register-resident, no LDS, no barriers.
// grid = (NHEAD, SPLITS), block = 64 (1 wave). lane = g*16 + t:
//   t = query index (0..15), g = 16-dim slice (0..3).
// Lane holds q[t][g-slice]; K/V tiles stream direct to registers; token
// pairing via DPP row rotations; softmax fully lane-local.
// ---------------------------------------------------------------------------
__global__ __launch_bounds__(64) void paged_attn(const float* __restrict__ kpool,
                                                 const float* __restrict__ vpool,
                                                 const int* __restrict__ block_ids,
                                                 const float* __restrict__ qws,
                                                 float* __restrict__ accws,
                                                 float* __restrict__ m_arr,
                                                 float* __restrict__ se_arr) {
    const int h = blockIdx.x;
    const int s = blockIdx.y;
    const int lane = threadIdx.x;
    const int t = lane & 15;
    const int g = lane >> 4;

    // hoist all physical block ids for this chunk (uniform scalar loads)
    int pbs[CHUNK / 16];
#pragma unroll
    for (int i = 0; i < CHUNK / 16; ++i)
        pbs[i] = block_ids[s * (CHUNK / 16) + i];

    float ql[16];
    {
        const float4* qp = (const float4*)(qws + ((size_t)(h * L_TOK + t)) * DHEAD + g * 16);
#pragma unroll
        for (int c = 0; c < 4; ++c) {
            float4 v = qp[c];
            ql[c * 4 + 0] = v.x; ql[c * 4 + 1] = v.y;
            ql[c * 4 + 2] = v.z; ql[c * 4 + 3] = v.w;
        }
    }

    float acc[16];
#pragma unroll
    for (int c = 0; c < 16; ++c) acc[c] = 0.f;
    float m_run = -INFINITY, se_run = 0.f;

    for (int tile = 0; tile < CHUNK / 16; ++tile) {
        const int tbase = s * CHUNK + tile * 16;
        const int pb = pbs[tile];
        const size_t rowbase = (((size_t)pb * BSZ + t) * NHEAD + h) * DHEAD + g * 16;

        float kk[16], vv[16];
        {
            const float4* k4 = (const float4*)(kpool + rowbase);
            const float4* v4 = (const float4*)(vpool + rowbase);
#pragma unroll
            for (int c = 0; c < 4; ++c) {
                float4 a = k4[c];
                kk[c * 4 + 0] = a.x; kk[c * 4 + 1] = a.y;
                kk[c * 4 + 2] = a.z; kk[c * 4 + 3] = a.w;
            }
#pragma unroll
            for (int c = 0; c < 4; ++c) {
                float a = 0.f; (void)a;
                float4 b = v4[c];
                vv[c * 4 + 0] = b.x; vv[c * 4 + 1] = b.y;
                vv[c * 4 + 2] = b.z; vv[c * 4 + 3] = b.w;
            }
        }

        // QK: step R pairs lane t with token sigma_R(t); partial over g-slice
        float s16[16];
        s16[0]  = qk_step<0>(ql, kk);   s16[1]  = qk_step<1>(ql, kk);
        s16[2]  = qk_step<2>(ql, kk);   s16[3]  = qk_step<3>(ql, kk);
        s16[4]  = qk_step<4>(ql, kk);   s16[5]  = qk_step<5>(ql, kk);
        s16[6]  = qk_step<6>(ql, kk);   s16[7]  = qk_step<7>(ql, kk);
        s16[8]  = qk_step<8>(ql, kk);   s16[9]  = qk_step<9>(ql, kk);
        s16[10] = qk_step<10>(ql, kk);  s16[11] = qk_step<11>(ql, kk);
        s16[12] = qk_step<12>(ql, kk);  s16[13] = qk_step<13>(ql, kk);
        s16[14] = qk_step<14>(ql, kk);  s16[15] = qk_step<15>(ql, kk);

        // reduce partials across the 4 g-slices (lane bits 4 and 5)
#pragma unroll
        for (int r = 0; r < 16; ++r) {
            s16[r] += __shfl_xor(s16[r], 16, 64);
            s16[r] += __shfl_xor(s16[r], 32, 64);
        }

        // causal mask: only the final tile is affected
        if (tbase + 15 > START_POS_C) {
            const int tv = t;
#define MASKJ(R) { int j = dppror_i<R>(tv); if (tbase + j > START_POS_C + t) s16[R] = -INFINITY; }
            MASKJ(0)  MASKJ(1)  MASKJ(2)  MASKJ(3)
            MASKJ(4)  MASKJ(5)  MASKJ(6)  MASKJ(7)
            MASKJ(8)  MASKJ(9)  MASKJ(10) MASKJ(11)
            MASKJ(12) MASKJ(13) MASKJ(14) MASKJ(15)
#undef MASKJ
        }

        // online softmax, lane-local (log2 domain; scale folded into q)
        float m16 = s16[0];
#pragma unroll
        for (int r = 1; r < 16; ++r) m16 = fmaxf(m16, s16[r]);
        const float m_new = fmaxf(m_run, m16);
        const float alpha = exp2f(m_run - m_new);
        float p[16];
        float tsum = 0.f;
#pragma unroll
        for (int r = 0; r < 16; ++r) {
            p[r] = exp2f(s16[r] - m_new);
            tsum += p[r];
        }
        se_run = se_run * alpha + tsum;
        m_run = m_new;
#pragma unroll
        for (int c = 0; c < 16; ++c) acc[c] *= alpha;

        // PV: same rotation pairing, accumulate out[t][g-slice]
        pv_step<0>(p[0], vv, acc);    pv_step<1>(p[1], vv, acc);
        pv_step<2>(p[2], vv, acc);    pv_step<3>(p[3], vv, acc);
        pv_step<4>(p[4], vv, acc);    pv_step<5>(p[5], vv, acc);
        pv_step<6>(p[6], vv, acc);    pv_step<7>(p[7], vv, acc);
        pv_step<8>(p[8], vv, acc);    pv_step<9>(p[9], vv, acc);
        pv_step<10>(p[10], vv, acc);  pv_step<11>(p[11], vv, acc);
        pv_step<12>(p[12], vv, acc);  pv_step<13>(p[13], vv, acc);
        pv_step<14>(p[14], vv, acc);  pv_step<15>(p[15], vv, acc);
    }

    const size_t obase = (((size_t)(h * SPLITS + s)) * L_TOK + t) * DHEAD + g * 16;
    float4* op = (float4*)(accws + obase);
    op[0] = make_float4(acc[0],  acc[1],  acc[2],  acc[3]);
    op[1] = make_float4(acc[4],  acc[5],  acc[6],  acc[7]);
    op[2] = make_float4(acc[8],  acc[9],  acc[10], acc[11]);
    op[3] = make_float4(acc[12], acc[13], acc[14], acc[15]);
    if (g == 0) {
        const size_t mb = (size_t)(h * SPLITS + s) * L_TOK + t;
        m_arr[mb] = m_run;
        se_arr[mb] = se_run;
    }
}

// ---------------------------------------------------------------------------
// Combine split partials -> attn_ws[l][h*64+d]. grid = H*L blocks x 256
// (4 waves; wave w handles splits w::4, then LDS merge).
// ---------------------------------------------------------------------------
__global__ __launch_bounds__(256) void combine(const float* __restrict__ accws,
                                               const float* __restrict__ m_arr,
                                               const float* __restrict__ se_arr,
                                               float* __restrict__ attnws) {
    const int h = blockIdx.x >> 4;
    const int l = blockIdx.x & 15;
    const int w = threadIdx.x >> 6;
    const int lane = threadIdx.x & 63;
    __shared__ float sm[4], sse[4], sacc[4][64];

    float M = -INFINITY, num = 0.f, den = 0.f;
#pragma unroll 4
    for (int s = w; s < SPLITS; s += 4) {
        const size_t idx = (size_t)(h * SPLITS + s) * L_TOK + l;
        const float ms = m_arr[idx];
        const float ses = se_arr[idx];
        const float a = accws[idx * DHEAD + lane];
        const float Mn = fmaxf(M, ms);
        const float c_old = exp2f(M - Mn);
        const float c_new = exp2f(ms - Mn);
        num = num * c_old + a * c_new;
        den = den * c_old + ses * c_new;
        M = Mn;
    }
    if (lane == 0) { sm[w] = M; sse[w] = den; }
    sacc[w][lane] = num;
    __syncthreads();
    if (w == 0) {
        const float M0 = fmaxf(fmaxf(sm[0], sm[1]), fmaxf(sm[2], sm[3]));
        float nn = 0.f, dd = 0.f;
#pragma unroll
        for (int i = 0; i < 4; ++i) {
            const float wgt = exp2f(sm[i] - M0);
            nn = fmaf(wgt, sacc[i][lane], nn);
            dd = fmaf(wgt, sse[i], dd);
        }
        attnws[(size_t)l * DMODEL + h * DHEAD + lane] = nn / dd;
    }
}

// ---------------------------------------------------------------------------
// Reduce split-K partials of final projection + bias -> d_out. grid 64x256.
// ---------------------------------------------------------------------------
__global__ __launch_bounds__(256) void proj_reduce(const float* __restrict__ part,
                                                   const float* __restrict__ bias,
                                                   float* __restrict__ out) {
    int tid = blockIdx.x * 256 + threadIdx.x;   // < 16384
    int n = tid & (DMODEL - 1);
    int l = tid >> 10;
    float s = bias[n];
#pragma unroll
    for (int kb = 0; kb < KSPLIT; ++kb)
        s += part[((size_t)kb * L_TOK + l) * DMODEL + n];
    out[tid] = s;
}

extern "C" void kernel_launch(void* const* d_in, const int* in_sizes, int n_in,
                              void* d_out, int out_size, void* d_ws, size_t ws_size,
                              hipStream_t stream) {
    const float* x       = (const float*)d_in[0];
    float* kpool         = (float*)d_in[1];
    float* vpool         = (float*)d_in[2];
    const float* W_attn  = (const float*)d_in[3];
    const float* b_attn  = (const float*)d_in[4];
    const float* W_proj  = (const float*)d_in[5];
    const float* b_proj  = (const float*)d_in[6];
    const int* block_ids = (const int*)d_in[7];
    float* ws  = (float*)d_ws;
    float* out = (float*)d_out;

    // 1) QKV projection (split-K partials)
    gemm_part<<<dim3(48, KSPLIT), 256, 0, stream>>>(x, W_attn, ws + OFF_QKVP, 3 * DMODEL);
    // 2) reduce + bias; q -> ws (scaled), new k/v -> pools (paged write)
    qkv_reduce_scatter<<<192, 256, 0, stream>>>(ws + OFF_QKVP, b_attn, block_ids,
                                                ws + OFF_QW, kpool, vpool);
    // 3) flash-decode attention over the full prefix
    paged_attn<<<dim3(NHEAD, SPLITS), 64, 0, stream>>>(kpool, vpool, block_ids,
                                                       ws + OFF_QW, ws + OFF_ACC,
                                                       ws + OFF_M, ws + OFF_SE);
    // 4) combine splits
    combine<<<NHEAD * L_TOK, 256, 0, stream>>>(ws + OFF_ACC, ws + OFF_M, ws + OFF_SE,
                                               ws + OFF_ATTN);
    // 5) output projection (split-K partials)
    gemm_part<<<dim3(16, KSPLIT), 256, 0, stream>>>(ws + OFF_ATTN, W_proj, ws + OFF_PROJP, DMODEL);
    // 6) reduce + bias -> d_out
    proj_reduce<<<64, 256, 0, stream>>>(ws + OFF_PROJP, b_proj, out);
}

// Round 4
// 207.812 us; speedup vs baseline: 1.5669x; 1.1143x over previous
//
#include <hip/hip_runtime.h>
#include <math.h>

#define L_TOK 16
#define DMODEL 1024
#define NHEAD 16
#define DHEAD 64
#define NBLK 1024
#define BSZ 16
#define START_POS_C 16368
#define TTOT 16384
#define SPLITS 128
#define CHUNK 128          // tokens per split (4 groups of 32)
#define KSPLIT 16
#define QSCALE (0.125f * 1.4426950408889634f)   // 1/sqrt(64) * log2(e)

// workspace offsets, in floats
#define OFF_QKVP 0                                          // 16*16*3072 = 786432
#define OFF_QW   (OFF_QKVP + KSPLIT * L_TOK * 3 * DMODEL)   // 786432
#define OFF_ACC  (OFF_QW + NHEAD * L_TOK * DHEAD)           // 802816
#define OFF_M    (OFF_ACC + NHEAD * SPLITS * L_TOK * DHEAD) // 2899968
#define OFF_SE   (OFF_M + NHEAD * SPLITS * L_TOK)           // 2932736
#define OFF_ATTN (OFF_SE + NHEAD * SPLITS * L_TOK)          // 2965504
#define OFF_PROJP (OFF_ATTN + L_TOK * DMODEL)               // 2981888
// end = 3244032 floats = 12.4 MB

typedef _Float16 half2_t __attribute__((ext_vector_type(2)));
typedef _Float16 half4_t __attribute__((ext_vector_type(4)));
typedef _Float16 half8_t __attribute__((ext_vector_type(8)));
typedef float float4v __attribute__((ext_vector_type(4)));

union H8 { _Float16 h[8]; half8_t v; };
union H4 { _Float16 h[4]; half4_t v; };

// ---------------------------------------------------------------------------
// Split-K partial GEMM (unchanged from r2).
// ---------------------------------------------------------------------------
__global__ __launch_bounds__(256) void gemm_part(const float* __restrict__ x,
                                                 const float* __restrict__ W,
                                                 float* __restrict__ part,
                                                 int ncols) {
    const int lane = threadIdx.x & 63;
    const int wv = threadIdx.x >> 6;
    const int n = blockIdx.x * 64 + lane;
    const int k0 = blockIdx.y * (DMODEL / KSPLIT);
    const float* xr = x + (size_t)(wv * 4) * DMODEL;
    float a0 = 0.f, a1 = 0.f, a2 = 0.f, a3 = 0.f;
#pragma unroll 8
    for (int k = k0; k < k0 + DMODEL / KSPLIT; ++k) {
        float w = W[(size_t)k * ncols + n];
        a0 = fmaf(xr[k], w, a0);
        a1 = fmaf(xr[DMODEL + k], w, a1);
        a2 = fmaf(xr[2 * DMODEL + k], w, a2);
        a3 = fmaf(xr[3 * DMODEL + k], w, a3);
    }
    size_t base = ((size_t)blockIdx.y * L_TOK + wv * 4) * ncols + n;
    part[base] = a0;
    part[base + (size_t)ncols] = a1;
    part[base + 2 * (size_t)ncols] = a2;
    part[base + 3 * (size_t)ncols] = a3;
}

// ---------------------------------------------------------------------------
// Reduce split-K partials of QKV, add bias, scatter (unchanged from r2).
// ---------------------------------------------------------------------------
__global__ __launch_bounds__(256) void qkv_reduce_scatter(const float* __restrict__ part,
                                                          const float* __restrict__ b_attn,
                                                          const int* __restrict__ block_ids,
                                                          float* __restrict__ qws,
                                                          float* __restrict__ kpool,
                                                          float* __restrict__ vpool) {
    int tid = blockIdx.x * 256 + threadIdx.x;
    int n = tid % (3 * DMODEL);
    int l = tid / (3 * DMODEL);
    float s = b_attn[n];
#pragma unroll
    for (int kb = 0; kb < KSPLIT; ++kb)
        s += part[((size_t)kb * L_TOK + l) * (3 * DMODEL) + n];
    int sec = n >> 10;
    int m = n & (DMODEL - 1);
    int h = m >> 6;
    int dd = m & 63;
    if (sec == 0) {
        qws[(h * L_TOK + l) * DHEAD + dd] = s * QSCALE;
    } else {
        int pos = START_POS_C + l;
        int blk = block_ids[pos >> 4];
        int off = pos & 15;
        size_t idx = (((size_t)blk * BSZ + off) * NHEAD + h) * DHEAD + dd;
        if (sec == 1) kpool[idx] = s;
        else          vpool[idx] = s;
    }
}

// ---------------------------------------------------------------------------
// Flash-decode paged attention via f16 MFMA. grid=(NHEAD,SPLITS), block=64.
// lane = quad*16 + c.  QK: S^T = K·Q^T with mfma_f32_16x16x32_f16
//   (A=K[m=token][k=d] row-contiguous; B=Q[k=d][n=query] row-contiguous).
//   C-layout: lane holds S^T[token=4*quad+r][query=c] — so P is ALREADY in
//   the A-frag layout of the 16x16x16 PV MFMA (A[m=query][k=4*quad+j]).
// Only V needs an LDS transpose (f32, RNE-cvt to f16 on read).
// Single wave per block: no barriers anywhere.
// ---------------------------------------------------------------------------
__global__ __launch_bounds__(64) void paged_attn(const float* __restrict__ kpool,
                                                 const float* __restrict__ vpool,
                                                 const int* __restrict__ block_ids,
                                                 const float* __restrict__ qws,
                                                 float* __restrict__ accws,
                                                 float* __restrict__ m_arr,
                                                 float* __restrict__ se_arr) {
    const int h = blockIdx.x;
    const int s = blockIdx.y;
    const int lane = threadIdx.x;
    const int c = lane & 15;        // query (for QK/PV frags) / token (for loads)
    const int quad = lane >> 4;

    // VT[buf][dv][tok]: V transposed, f32, row stride 36 (16B-aligned rows,
    // balanced bank coverage for the b128 reads). 18.4 KB.
    __shared__ float VT[2][64][36];

    // Q B-frags (held for the whole kernel): B[k=quad*8+j][n=c] = Q[c][quad*8+j]
    H8 qb0, qb1;
    {
        const float* qr = qws + ((size_t)(h * L_TOK + c)) * DHEAD + quad * 8;
        float4 q0 = *(const float4*)(qr);
        float4 q1 = *(const float4*)(qr + 4);
        float4 q2 = *(const float4*)(qr + 32);
        float4 q3 = *(const float4*)(qr + 36);
        qb0.h[0] = (_Float16)q0.x; qb0.h[1] = (_Float16)q0.y;
        qb0.h[2] = (_Float16)q0.z; qb0.h[3] = (_Float16)q0.w;
        qb0.h[4] = (_Float16)q1.x; qb0.h[5] = (_Float16)q1.y;
        qb0.h[6] = (_Float16)q1.z; qb0.h[7] = (_Float16)q1.w;
        qb1.h[0] = (_Float16)q2.x; qb1.h[1] = (_Float16)q2.y;
        qb1.h[2] = (_Float16)q2.z; qb1.h[3] = (_Float16)q2.w;
        qb1.h[4] = (_Float16)q3.x; qb1.h[5] = (_Float16)q3.y;
        qb1.h[6] = (_Float16)q3.z; qb1.h[7] = (_Float16)q3.w;
    }

    float4v acc[4];
#pragma unroll
    for (int i = 0; i < 4; ++i) acc[i] = (float4v){0.f, 0.f, 0.f, 0.f};
    float m_run = -INFINITY, se_run = 0.f;

    const int blk0 = s * (CHUNK / 16);

#pragma unroll 2
    for (int grp = 0; grp < CHUNK / 32; ++grp) {
        const int tb = s * CHUNK + grp * 32;
        const int buf = grp & 1;
        const int pb0 = block_ids[blk0 + 2 * grp];
        const int pb1 = block_ids[blk0 + 2 * grp + 1];

        // ---- global loads: K and V rows for both 16-token tiles ----
        const float* kr0 = kpool + (((size_t)pb0 * BSZ + c) * NHEAD + h) * DHEAD + quad * 8;
        const float* kr1 = kpool + (((size_t)pb1 * BSZ + c) * NHEAD + h) * DHEAD + quad * 8;
        const float* vr0 = vpool + (((size_t)pb0 * BSZ + c) * NHEAD + h) * DHEAD + quad * 8;
        const float* vr1 = vpool + (((size_t)pb1 * BSZ + c) * NHEAD + h) * DHEAD + quad * 8;
        float4 k0a = *(const float4*)(kr0);      float4 k0b = *(const float4*)(kr0 + 4);
        float4 k0c = *(const float4*)(kr0 + 32); float4 k0d = *(const float4*)(kr0 + 36);
        float4 k1a = *(const float4*)(kr1);      float4 k1b = *(const float4*)(kr1 + 4);
        float4 k1c = *(const float4*)(kr1 + 32); float4 k1d = *(const float4*)(kr1 + 36);
        float4 v0a = *(const float4*)(vr0);      float4 v0b = *(const float4*)(vr0 + 4);
        float4 v0c = *(const float4*)(vr0 + 32); float4 v0d = *(const float4*)(vr0 + 36);
        float4 v1a = *(const float4*)(vr1);      float4 v1b = *(const float4*)(vr1 + 4);
        float4 v1c = *(const float4*)(vr1 + 32); float4 v1d = *(const float4*)(vr1 + 36);

        // ---- V -> LDS transpose (f32): VT[dv][tok] ----
        {
            float* w0 = &VT[buf][quad * 8][c];           // tile0, d-half 0
            w0[0*36]=v0a.x; w0[1*36]=v0a.y; w0[2*36]=v0a.z; w0[3*36]=v0a.w;
            w0[4*36]=v0b.x; w0[5*36]=v0b.y; w0[6*36]=v0b.z; w0[7*36]=v0b.w;
            float* w1 = &VT[buf][32 + quad * 8][c];      // tile0, d-half 1
            w1[0*36]=v0c.x; w1[1*36]=v0c.y; w1[2*36]=v0c.z; w1[3*36]=v0c.w;
            w1[4*36]=v0d.x; w1[5*36]=v0d.y; w1[6*36]=v0d.z; w1[7*36]=v0d.w;
            float* w2 = &VT[buf][quad * 8][16 + c];      // tile1, d-half 0
            w2[0*36]=v1a.x; w2[1*36]=v1a.y; w2[2*36]=v1a.z; w2[3*36]=v1a.w;
            w2[4*36]=v1b.x; w2[5*36]=v1b.y; w2[6*36]=v1b.z; w2[7*36]=v1b.w;
            float* w3 = &VT[buf][32 + quad * 8][16 + c]; // tile1, d-half 1
            w3[0*36]=v1c.x; w3[1*36]=v1c.y; w3[2*36]=v1c.z; w3[3*36]=v1c.w;
            w3[4*36]=v1d.x; w3[5*36]=v1d.y; w3[6*36]=v1d.z; w3[7*36]=v1d.w;
        }

        // ---- QK MFMAs: S^T per tile (RNE f32->f16 on K) ----
        const float4v z4 = {0.f, 0.f, 0.f, 0.f};
        H8 ka, kb;
        ka.h[0]=(_Float16)k0a.x; ka.h[1]=(_Float16)k0a.y; ka.h[2]=(_Float16)k0a.z; ka.h[3]=(_Float16)k0a.w;
        ka.h[4]=(_Float16)k0b.x; ka.h[5]=(_Float16)k0b.y; ka.h[6]=(_Float16)k0b.z; ka.h[7]=(_Float16)k0b.w;
        kb.h[0]=(_Float16)k0c.x; kb.h[1]=(_Float16)k0c.y; kb.h[2]=(_Float16)k0c.z; kb.h[3]=(_Float16)k0c.w;
        kb.h[4]=(_Float16)k0d.x; kb.h[5]=(_Float16)k0d.y; kb.h[6]=(_Float16)k0d.z; kb.h[7]=(_Float16)k0d.w;
        float4v st0 = __builtin_amdgcn_mfma_f32_16x16x32_f16(ka.v, qb0.v, z4, 0, 0, 0);
        st0 = __builtin_amdgcn_mfma_f32_16x16x32_f16(kb.v, qb1.v, st0, 0, 0, 0);
        ka.h[0]=(_Float16)k1a.x; ka.h[1]=(_Float16)k1a.y; ka.h[2]=(_Float16)k1a.z; ka.h[3]=(_Float16)k1a.w;
        ka.h[4]=(_Float16)k1b.x; ka.h[5]=(_Float16)k1b.y; ka.h[6]=(_Float16)k1b.z; ka.h[7]=(_Float16)k1b.w;
        kb.h[0]=(_Float16)k1c.x; kb.h[1]=(_Float16)k1c.y; kb.h[2]=(_Float16)k1c.z; kb.h[3]=(_Float16)k1c.w;
        kb.h[4]=(_Float16)k1d.x; kb.h[5]=(_Float16)k1d.y; kb.h[6]=(_Float16)k1d.z; kb.h[7]=(_Float16)k1d.w;
        float4v st1 = __builtin_amdgcn_mfma_f32_16x16x32_f16(ka.v, qb0.v, z4, 0, 0, 0);
        st1 = __builtin_amdgcn_mfma_f32_16x16x32_f16(kb.v, qb1.v, st1, 0, 0, 0);

        // ---- causal mask (only the very last group of the last split) ----
        if (tb + 31 > START_POS_C) {
#pragma unroll
            for (int r = 0; r < 4; ++r) {
                if (tb + 4 * quad + r > START_POS_C + c)      st0[r] = -INFINITY;
                if (tb + 16 + 4 * quad + r > START_POS_C + c) st1[r] = -INFINITY;
            }
        }

        // ---- online softmax (lane state is per query c, replicated 4x) ----
        float tm = fmaxf(fmaxf(fmaxf(st0[0], st0[1]), fmaxf(st0[2], st0[3])),
                         fmaxf(fmaxf(st1[0], st1[1]), fmaxf(st1[2], st1[3])));
        tm = fmaxf(tm, __shfl_xor(tm, 16, 64));
        tm = fmaxf(tm, __shfl_xor(tm, 32, 64));
        const float m_new = fmaxf(m_run, tm);
        const float alpha = exp2f(m_run - m_new);
        float p[8];
        p[0] = exp2f(st0[0] - m_new); p[1] = exp2f(st0[1] - m_new);
        p[2] = exp2f(st0[2] - m_new); p[3] = exp2f(st0[3] - m_new);
        p[4] = exp2f(st1[0] - m_new); p[5] = exp2f(st1[1] - m_new);
        p[6] = exp2f(st1[2] - m_new); p[7] = exp2f(st1[3] - m_new);
        // round p to f16 FIRST, and sum the rounded values (keeps numerator
        // and denominator consistently rounded — no systematic bias)
        H4 pa0, pa1;
        pa0.h[0]=(_Float16)p[0]; pa0.h[1]=(_Float16)p[1];
        pa0.h[2]=(_Float16)p[2]; pa0.h[3]=(_Float16)p[3];
        pa1.h[0]=(_Float16)p[4]; pa1.h[1]=(_Float16)p[5];
        pa1.h[2]=(_Float16)p[6]; pa1.h[3]=(_Float16)p[7];
        float ts = ((float)pa0.h[0] + (float)pa0.h[1]) + ((float)pa0.h[2] + (float)pa0.h[3])
                 + ((float)pa1.h[0] + (float)pa1.h[1]) + ((float)pa1.h[2] + (float)pa1.h[3]);
        ts += __shfl_xor(ts, 16, 64);
        ts += __shfl_xor(ts, 32, 64);
        se_run = se_run * alpha + ts;
        m_run = m_new;

        // ---- rescale acc: rows of acc are queries 4*quad+r ----
        float ar[4];
#pragma unroll
        for (int r = 0; r < 4; ++r) ar[r] = __shfl(alpha, quad * 4 + r, 64);
#pragma unroll
        for (int ndv = 0; ndv < 4; ++ndv)
#pragma unroll
            for (int r = 0; r < 4; ++r) acc[ndv][r] *= ar[r];

        // ---- PV MFMAs: B[k=4*quad+j][n=dv=16*ndv+c] from VT ----
#pragma unroll
        for (int tau = 0; tau < 2; ++tau) {
            const half4_t pf = tau ? pa1.v : pa0.v;
#pragma unroll
            for (int ndv = 0; ndv < 4; ++ndv) {
                float4 vb = *(const float4*)&VT[buf][16 * ndv + c][16 * tau + 4 * quad];
                H4 bf;
                bf.h[0] = (_Float16)vb.x; bf.h[1] = (_Float16)vb.y;
                bf.h[2] = (_Float16)vb.z; bf.h[3] = (_Float16)vb.w;
                acc[ndv] = __builtin_amdgcn_mfma_f32_16x16x16f16(pf, bf.v, acc[ndv], 0, 0, 0);
            }
        }
    }

    // ---- epilogue: unnormalized acc + (m, se) per (h, split, query) ----
    const size_t ob = (size_t)(h * SPLITS + s) * L_TOK * DHEAD;
#pragma unroll
    for (int ndv = 0; ndv < 4; ++ndv)
#pragma unroll
        for (int r = 0; r < 4; ++r)
            accws[ob + (size_t)(4 * quad + r) * DHEAD + 16 * ndv + c] = acc[ndv][r];
    if (quad == 0) {
        const size_t mb = (size_t)(h * SPLITS + s) * L_TOK + c;
        m_arr[mb] = m_run;
        se_arr[mb] = se_run;
    }
}

// ---------------------------------------------------------------------------
// Combine split partials (unchanged from r2).
// ---------------------------------------------------------------------------
__global__ __launch_bounds__(256) void combine(const float* __restrict__ accws,
                                               const float* __restrict__ m_arr,
                                               const float* __restrict__ se_arr,
                                               float* __restrict__ attnws) {
    const int h = blockIdx.x >> 4;
    const int l = blockIdx.x & 15;
    const int w = threadIdx.x >> 6;
    const int lane = threadIdx.x & 63;
    __shared__ float sm[4], sse[4], sacc[4][64];

    float M = -INFINITY, num = 0.f, den = 0.f;
#pragma unroll 4
    for (int s = w; s < SPLITS; s += 4) {
        const size_t idx = (size_t)(h * SPLITS + s) * L_TOK + l;
        const float ms = m_arr[idx];
        const float ses = se_arr[idx];
        const float a = accws[idx * DHEAD + lane];
        const float Mn = fmaxf(M, ms);
        const float c_old = exp2f(M - Mn);
        const float c_new = exp2f(ms - Mn);
        num = num * c_old + a * c_new;
        den = den * c_old + ses * c_new;
        M = Mn;
    }
    if (lane == 0) { sm[w] = M; sse[w] = den; }
    sacc[w][lane] = num;
    __syncthreads();
    if (w == 0) {
        const float M0 = fmaxf(fmaxf(sm[0], sm[1]), fmaxf(sm[2], sm[3]));
        float nn = 0.f, dd = 0.f;
#pragma unroll
        for (int i = 0; i < 4; ++i) {
            const float wgt = exp2f(sm[i] - M0);
            nn = fmaf(wgt, sacc[i][lane], nn);
            dd = fmaf(wgt, sse[i], dd);
        }
        attnws[(size_t)l * DMODEL + h * DHEAD + lane] = nn / dd;
    }
}

// ---------------------------------------------------------------------------
// Reduce split-K partials of final projection + bias -> d_out (unchanged).
// ---------------------------------------------------------------------------
__global__ __launch_bounds__(256) void proj_reduce(const float* __restrict__ part,
                                                   const float* __restrict__ bias,
                                                   float* __restrict__ out) {
    int tid = blockIdx.x * 256 + threadIdx.x;   // < 16384
    int n = tid & (DMODEL - 1);
    int l = tid >> 10;
    float s = bias[n];
#pragma unroll
    for (int kb = 0; kb < KSPLIT; ++kb)
        s += part[((size_t)kb * L_TOK + l) * DMODEL + n];
    out[tid] = s;
}

extern "C" void kernel_launch(void* const* d_in, const int* in_sizes, int n_in,
                              void* d_out, int out_size, void* d_ws, size_t ws_size,
                              hipStream_t stream) {
    const float* x       = (const float*)d_in[0];
    float* kpool         = (float*)d_in[1];
    float* vpool         = (float*)d_in[2];
    const float* W_attn  = (const float*)d_in[3];
    const float* b_attn  = (const float*)d_in[4];
    const float* W_proj  = (const float*)d_in[5];
    const float* b_proj  = (const float*)d_in[6];
    const int* block_ids = (const int*)d_in[7];
    float* ws  = (float*)d_ws;
    float* out = (float*)d_out;

    // 1) QKV projection (split-K partials)
    gemm_part<<<dim3(48, KSPLIT), 256, 0, stream>>>(x, W_attn, ws + OFF_QKVP, 3 * DMODEL);
    // 2) reduce + bias; q -> ws (scaled), new k/v -> pools (paged write)
    qkv_reduce_scatter<<<192, 256, 0, stream>>>(ws + OFF_QKVP, b_attn, block_ids,
                                                ws + OFF_QW, kpool, vpool);
    // 3) flash-decode attention over the full prefix (f16 MFMA)
    paged_attn<<<dim3(NHEAD, SPLITS), 64, 0, stream>>>(kpool, vpool, block_ids,
                                                       ws + OFF_QW, ws + OFF_ACC,
                                                       ws + OFF_M, ws + OFF_SE);
    // 4) combine splits
    combine<<<NHEAD * L_TOK, 256, 0, stream>>>(ws + OFF_ACC, ws + OFF_M, ws + OFF_SE,
                                               ws + OFF_ATTN);
    // 5) output projection (split-K partials)
    gemm_part<<<dim3(16, KSPLIT), 256, 0, stream>>>(ws + OFF_ATTN, W_proj, ws + OFF_PROJP, DMODEL);
    // 6) reduce + bias -> d_out
    proj_reduce<<<64, 256, 0, stream>>>(ws + OFF_PROJP, b_proj, out);
}

// Round 5
// 206.592 us; speedup vs baseline: 1.5761x; 1.0059x over previous
//
#include <hip/hip_runtime.h>
#include <math.h>

#define L_TOK 16
#define DMODEL 1024
#define NHEAD 16
#define DHEAD 64
#define NBLK 1024
#define BSZ 16
#define START_POS_C 16368
#define TTOT 16384
#define SPLITS 128
#define CHUNK 128          // tokens per block (4 waves x 32 tokens)
#define KSPLIT 16
#define QSCALE (0.125f * 1.4426950408889634f)   // 1/sqrt(64) * log2(e)

// workspace offsets, in floats
#define OFF_QKVP 0                                          // 16*16*3072 = 786432
#define OFF_QW   (OFF_QKVP + KSPLIT * L_TOK * 3 * DMODEL)   // 786432
#define OFF_ACC  (OFF_QW + NHEAD * L_TOK * DHEAD)           // 802816
#define OFF_M    (OFF_ACC + NHEAD * SPLITS * L_TOK * DHEAD) // 2899968
#define OFF_SE   (OFF_M + NHEAD * SPLITS * L_TOK)           // 2932736
#define OFF_ATTN (OFF_SE + NHEAD * SPLITS * L_TOK)          // 2965504
#define OFF_PROJP (OFF_ATTN + L_TOK * DMODEL)               // 2981888
// end = 3244032 floats = 12.4 MB (round-1-proven scale)

typedef _Float16 half4_t __attribute__((ext_vector_type(4)));
typedef _Float16 half8_t __attribute__((ext_vector_type(8)));
typedef float float4v __attribute__((ext_vector_type(4)));

union H8 { _Float16 h[8]; half8_t v; };
union H4 { _Float16 h[4]; half4_t v; };

// ---------------------------------------------------------------------------
// Split-K partial GEMM, vectorized: each lane owns 4 cols (float4 W loads),
// each wave owns 4 rows. grid = (ncols/256, KSPLIT), block = 256.
// ---------------------------------------------------------------------------
__global__ __launch_bounds__(256) void gemm_part(const float* __restrict__ x,
                                                 const float* __restrict__ W,
                                                 float* __restrict__ part,
                                                 int ncols) {
    const int lane = threadIdx.x & 63;
    const int wv = threadIdx.x >> 6;
    const int n = blockIdx.x * 256 + lane * 4;
    const int k0 = blockIdx.y * (DMODEL / KSPLIT);
    const float* xr = x + (size_t)(wv * 4) * DMODEL;
    float4v a0 = {0.f,0.f,0.f,0.f}, a1 = a0, a2 = a0, a3 = a0;
#pragma unroll 4
    for (int k = k0; k < k0 + DMODEL / KSPLIT; ++k) {
        float4v w4 = *(const float4v*)&W[(size_t)k * ncols + n];
        float x0 = xr[k];
        float x1 = xr[DMODEL + k];
        float x2 = xr[2 * DMODEL + k];
        float x3 = xr[3 * DMODEL + k];
        a0 += w4 * x0;
        a1 += w4 * x1;
        a2 += w4 * x2;
        a3 += w4 * x3;
    }
    size_t base = ((size_t)blockIdx.y * L_TOK + wv * 4) * ncols + n;
    *(float4v*)&part[base] = a0;
    *(float4v*)&part[base + (size_t)ncols] = a1;
    *(float4v*)&part[base + 2 * (size_t)ncols] = a2;
    *(float4v*)&part[base + 3 * (size_t)ncols] = a3;
}

// ---------------------------------------------------------------------------
// Reduce split-K partials of QKV, add bias, scatter (unchanged).
// ---------------------------------------------------------------------------
__global__ __launch_bounds__(256) void qkv_reduce_scatter(const float* __restrict__ part,
                                                          const float* __restrict__ b_attn,
                                                          const int* __restrict__ block_ids,
                                                          float* __restrict__ qws,
                                                          float* __restrict__ kpool,
                                                          float* __restrict__ vpool) {
    int tid = blockIdx.x * 256 + threadIdx.x;
    int n = tid % (3 * DMODEL);
    int l = tid / (3 * DMODEL);
    float s = b_attn[n];
#pragma unroll
    for (int kb = 0; kb < KSPLIT; ++kb)
        s += part[((size_t)kb * L_TOK + l) * (3 * DMODEL) + n];
    int sec = n >> 10;
    int m = n & (DMODEL - 1);
    int h = m >> 6;
    int dd = m & 63;
    if (sec == 0) {
        qws[(h * L_TOK + l) * DHEAD + dd] = s * QSCALE;
    } else {
        int pos = START_POS_C + l;
        int blk = block_ids[pos >> 4];
        int off = pos & 15;
        size_t idx = (((size_t)blk * BSZ + off) * NHEAD + h) * DHEAD + dd;
        if (sec == 1) kpool[idx] = s;
        else          vpool[idx] = s;
    }
}

// ---------------------------------------------------------------------------
// Flash-decode paged attention v5. grid = (NHEAD, SPLITS), block = 256
// (4 waves; wave w owns tokens [s*128 + 32w, +32), straight-line, single-shot
// softmax). All 40 VMEM loads issued before any use. V gathered direct to
// registers in PV B-frag layout (4 lines/instr, fully consumed). One
// __syncthreads + LDS merge of the 4 wave-partials; combine() unchanged.
// ---------------------------------------------------------------------------
__global__ __launch_bounds__(256, 4) void paged_attn(const float* __restrict__ kpool,
                                                     const float* __restrict__ vpool,
                                                     const int* __restrict__ block_ids,
                                                     const float* __restrict__ qws,
                                                     float* __restrict__ accws,
                                                     float* __restrict__ m_arr,
                                                     float* __restrict__ se_arr) {
    const int h = blockIdx.x;
    const int s = blockIdx.y;
    const int tid = threadIdx.x;
    const int w = tid >> 6;
    const int lane = tid & 63;
    const int c = lane & 15;
    const int quad = lane >> 4;

    __shared__ __align__(16) float sacc[4][16][68];   // stride 68: 2-way banks, 16B rows
    __shared__ float sm[4][16], sse[4][16];

    const int pb0 = block_ids[s * 8 + 2 * w];
    const int pb1 = block_ids[s * 8 + 2 * w + 1];
    const int tb0 = s * CHUNK + w * 32;
    const int tb1 = tb0 + 16;

    // ---- issue ALL global loads up front ----
    // Q rows (retired first)
    const float* qr = qws + ((size_t)(h * L_TOK + c)) * DHEAD + quad * 8;
    float4 q0 = *(const float4*)(qr);
    float4 q1 = *(const float4*)(qr + 4);
    float4 q2 = *(const float4*)(qr + 32);
    float4 q3 = *(const float4*)(qr + 36);
    // K A-frag rows: token c of each tile, cols [quad*8,+8) and [32+quad*8,+8)
    const float* kr0 = kpool + (((size_t)pb0 * BSZ + c) * NHEAD + h) * DHEAD + quad * 8;
    const float* kr1 = kpool + (((size_t)pb1 * BSZ + c) * NHEAD + h) * DHEAD + quad * 8;
    float4 k0a = *(const float4*)(kr0);      float4 k0b = *(const float4*)(kr0 + 4);
    float4 k0c = *(const float4*)(kr0 + 32); float4 k0d = *(const float4*)(kr0 + 36);
    float4 k1a = *(const float4*)(kr1);      float4 k1b = *(const float4*)(kr1 + 4);
    float4 k1c = *(const float4*)(kr1 + 32); float4 k1d = *(const float4*)(kr1 + 36);
    // V gathered in PV B-frag layout: v[tile][j][ndv] = V[4*quad+j][16*ndv+c]
    float v0[4][4], v1[4][4];
    {
        const float* vb0 = vpool + ((size_t)pb0 * BSZ * NHEAD + h) * DHEAD + c;
        const float* vb1 = vpool + ((size_t)pb1 * BSZ * NHEAD + h) * DHEAD + c;
#pragma unroll
        for (int j = 0; j < 4; ++j) {
            const float* r0 = vb0 + (size_t)(4 * quad + j) * (NHEAD * DHEAD);
            const float* r1 = vb1 + (size_t)(4 * quad + j) * (NHEAD * DHEAD);
#pragma unroll
            for (int ndv = 0; ndv < 4; ++ndv) {
                v0[j][ndv] = r0[16 * ndv];
                v1[j][ndv] = r1[16 * ndv];
            }
        }
    }

    // ---- Q B-frags ----
    H8 qb0, qb1;
    qb0.h[0]=(_Float16)q0.x; qb0.h[1]=(_Float16)q0.y; qb0.h[2]=(_Float16)q0.z; qb0.h[3]=(_Float16)q0.w;
    qb0.h[4]=(_Float16)q1.x; qb0.h[5]=(_Float16)q1.y; qb0.h[6]=(_Float16)q1.z; qb0.h[7]=(_Float16)q1.w;
    qb1.h[0]=(_Float16)q2.x; qb1.h[1]=(_Float16)q2.y; qb1.h[2]=(_Float16)q2.z; qb1.h[3]=(_Float16)q2.w;
    qb1.h[4]=(_Float16)q3.x; qb1.h[5]=(_Float16)q3.y; qb1.h[6]=(_Float16)q3.z; qb1.h[7]=(_Float16)q3.w;

    // ---- QK MFMAs: S^T[token][query] per tile ----
    const float4v z4 = {0.f, 0.f, 0.f, 0.f};
    H8 ka, kb;
    ka.h[0]=(_Float16)k0a.x; ka.h[1]=(_Float16)k0a.y; ka.h[2]=(_Float16)k0a.z; ka.h[3]=(_Float16)k0a.w;
    ka.h[4]=(_Float16)k0b.x; ka.h[5]=(_Float16)k0b.y; ka.h[6]=(_Float16)k0b.z; ka.h[7]=(_Float16)k0b.w;
    kb.h[0]=(_Float16)k0c.x; kb.h[1]=(_Float16)k0c.y; kb.h[2]=(_Float16)k0c.z; kb.h[3]=(_Float16)k0c.w;
    kb.h[4]=(_Float16)k0d.x; kb.h[5]=(_Float16)k0d.y; kb.h[6]=(_Float16)k0d.z; kb.h[7]=(_Float16)k0d.w;
    float4v st0 = __builtin_amdgcn_mfma_f32_16x16x32_f16(ka.v, qb0.v, z4, 0, 0, 0);
    st0 = __builtin_amdgcn_mfma_f32_16x16x32_f16(kb.v, qb1.v, st0, 0, 0, 0);
    ka.h[0]=(_Float16)k1a.x; ka.h[1]=(_Float16)k1a.y; ka.h[2]=(_Float16)k1a.z; ka.h[3]=(_Float16)k1a.w;
    ka.h[4]=(_Float16)k1b.x; ka.h[5]=(_Float16)k1b.y; ka.h[6]=(_Float16)k1b.z; ka.h[7]=(_Float16)k1b.w;
    kb.h[0]=(_Float16)k1c.x; kb.h[1]=(_Float16)k1c.y; kb.h[2]=(_Float16)k1c.z; kb.h[3]=(_Float16)k1c.w;
    kb.h[4]=(_Float16)k1d.x; kb.h[5]=(_Float16)k1d.y; kb.h[6]=(_Float16)k1d.z; kb.h[7]=(_Float16)k1d.w;
    float4v st1 = __builtin_amdgcn_mfma_f32_16x16x32_f16(ka.v, qb0.v, z4, 0, 0, 0);
    st1 = __builtin_amdgcn_mfma_f32_16x16x32_f16(kb.v, qb1.v, st1, 0, 0, 0);

    // ---- causal mask (per tile; only the last block's wave 3 is affected) ----
    if (tb0 + 15 > START_POS_C) {
#pragma unroll
        for (int r = 0; r < 4; ++r)
            if (tb0 + 4 * quad + r > START_POS_C + c) st0[r] = -INFINITY;
    }
    if (tb1 + 15 > START_POS_C) {
#pragma unroll
        for (int r = 0; r < 4; ++r)
            if (tb1 + 4 * quad + r > START_POS_C + c) st1[r] = -INFINITY;
    }

    // ---- single-shot softmax over this wave's 32 tokens (per query c) ----
    float tm = fmaxf(fmaxf(fmaxf(st0[0], st0[1]), fmaxf(st0[2], st0[3])),
                     fmaxf(fmaxf(st1[0], st1[1]), fmaxf(st1[2], st1[3])));
    tm = fmaxf(tm, __shfl_xor(tm, 16, 64));
    tm = fmaxf(tm, __shfl_xor(tm, 32, 64));
    H4 pa0, pa1;
    pa0.h[0]=(_Float16)exp2f(st0[0]-tm); pa0.h[1]=(_Float16)exp2f(st0[1]-tm);
    pa0.h[2]=(_Float16)exp2f(st0[2]-tm); pa0.h[3]=(_Float16)exp2f(st0[3]-tm);
    pa1.h[0]=(_Float16)exp2f(st1[0]-tm); pa1.h[1]=(_Float16)exp2f(st1[1]-tm);
    pa1.h[2]=(_Float16)exp2f(st1[2]-tm); pa1.h[3]=(_Float16)exp2f(st1[3]-tm);
    float ts = ((float)pa0.h[0] + (float)pa0.h[1]) + ((float)pa0.h[2] + (float)pa0.h[3])
             + ((float)pa1.h[0] + (float)pa1.h[1]) + ((float)pa1.h[2] + (float)pa1.h[3]);
    ts += __shfl_xor(ts, 16, 64);
    ts += __shfl_xor(ts, 32, 64);

    // ---- PV MFMAs (no rescale — single shot) ----
    float4v acc[4];
#pragma unroll
    for (int i = 0; i < 4; ++i) acc[i] = z4;
#pragma unroll
    for (int ndv = 0; ndv < 4; ++ndv) {
        H4 bf;
        bf.h[0]=(_Float16)v0[0][ndv]; bf.h[1]=(_Float16)v0[1][ndv];
        bf.h[2]=(_Float16)v0[2][ndv]; bf.h[3]=(_Float16)v0[3][ndv];
        acc[ndv] = __builtin_amdgcn_mfma_f32_16x16x16f16(pa0.v, bf.v, acc[ndv], 0, 0, 0);
        bf.h[0]=(_Float16)v1[0][ndv]; bf.h[1]=(_Float16)v1[1][ndv];
        bf.h[2]=(_Float16)v1[2][ndv]; bf.h[3]=(_Float16)v1[3][ndv];
        acc[ndv] = __builtin_amdgcn_mfma_f32_16x16x16f16(pa1.v, bf.v, acc[ndv], 0, 0, 0);
    }

    // ---- in-block merge of 4 wave-partials ----
#pragma unroll
    for (int ndv = 0; ndv < 4; ++ndv)
#pragma unroll
        for (int r = 0; r < 4; ++r)
            sacc[w][4 * quad + r][16 * ndv + c] = acc[ndv][r];
    if (quad == 0) { sm[w][c] = tm; sse[w][c] = ts; }
    __syncthreads();

    const int q = tid >> 4;
    const int dseg = tid & 15;
    float m0 = sm[0][q], m1 = sm[1][q], m2 = sm[2][q], m3 = sm[3][q];
    float M = fmaxf(fmaxf(m0, m1), fmaxf(m2, m3));
    float u0 = exp2f(m0 - M), u1 = exp2f(m1 - M), u2 = exp2f(m2 - M), u3 = exp2f(m3 - M);
    float den = u0 * sse[0][q] + u1 * sse[1][q] + u2 * sse[2][q] + u3 * sse[3][q];
    float4v num = u0 * (*(const float4v*)&sacc[0][q][4 * dseg])
                + u1 * (*(const float4v*)&sacc[1][q][4 * dseg])
                + u2 * (*(const float4v*)&sacc[2][q][4 * dseg])
                + u3 * (*(const float4v*)&sacc[3][q][4 * dseg]);
    const size_t ob = ((size_t)(h * SPLITS + s) * L_TOK + q) * DHEAD + 4 * dseg;
    *(float4v*)&accws[ob] = num;
    if (dseg == 0) {
        const size_t mb = (size_t)(h * SPLITS + s) * L_TOK + q;
        m_arr[mb] = M;
        se_arr[mb] = den;
    }
}

// ---------------------------------------------------------------------------
// Combine split partials (unchanged).
// ---------------------------------------------------------------------------
__global__ __launch_bounds__(256) void combine(const float* __restrict__ accws,
                                               const float* __restrict__ m_arr,
                                               const float* __restrict__ se_arr,
                                               float* __restrict__ attnws) {
    const int h = blockIdx.x >> 4;
    const int l = blockIdx.x & 15;
    const int w = threadIdx.x >> 6;
    const int lane = threadIdx.x & 63;
    __shared__ float sm[4], sse[4], sacc[4][64];

    float M = -INFINITY, num = 0.f, den = 0.f;
#pragma unroll 4
    for (int s = w; s < SPLITS; s += 4) {
        const size_t idx = (size_t)(h * SPLITS + s) * L_TOK + l;
        const float ms = m_arr[idx];
        const float ses = se_arr[idx];
        const float a = accws[idx * DHEAD + lane];
        const float Mn = fmaxf(M, ms);
        const float c_old = exp2f(M - Mn);
        const float c_new = exp2f(ms - Mn);
        num = num * c_old + a * c_new;
        den = den * c_old + ses * c_new;
        M = Mn;
    }
    if (lane == 0) { sm[w] = M; sse[w] = den; }
    sacc[w][lane] = num;
    __syncthreads();
    if (w == 0) {
        const float M0 = fmaxf(fmaxf(sm[0], sm[1]), fmaxf(sm[2], sm[3]));
        float nn = 0.f, dd = 0.f;
#pragma unroll
        for (int i = 0; i < 4; ++i) {
            const float wgt = exp2f(sm[i] - M0);
            nn = fmaf(wgt, sacc[i][lane], nn);
            dd = fmaf(wgt, sse[i], dd);
        }
        attnws[(size_t)l * DMODEL + h * DHEAD + lane] = nn / dd;
    }
}

// ---------------------------------------------------------------------------
// Reduce split-K partials of final projection + bias -> d_out (unchanged).
// ---------------------------------------------------------------------------
__global__ __launch_bounds__(256) void proj_reduce(const float* __restrict__ part,
                                                   const float* __restrict__ bias,
                                                   float* __restrict__ out) {
    int tid = blockIdx.x * 256 + threadIdx.x;   // < 16384
    int n = tid & (DMODEL - 1);
    int l = tid >> 10;
    float s = bias[n];
#pragma unroll
    for (int kb = 0; kb < KSPLIT; ++kb)
        s += part[((size_t)kb * L_TOK + l) * DMODEL + n];
    out[tid] = s;
}

extern "C" void kernel_launch(void* const* d_in, const int* in_sizes, int n_in,
                              void* d_out, int out_size, void* d_ws, size_t ws_size,
                              hipStream_t stream) {
    const float* x       = (const float*)d_in[0];
    float* kpool         = (float*)d_in[1];
    float* vpool         = (float*)d_in[2];
    const float* W_attn  = (const float*)d_in[3];
    const float* b_attn  = (const float*)d_in[4];
    const float* W_proj  = (const float*)d_in[5];
    const float* b_proj  = (const float*)d_in[6];
    const int* block_ids = (const int*)d_in[7];
    float* ws  = (float*)d_ws;
    float* out = (float*)d_out;

    // 1) QKV projection (split-K partials)
    gemm_part<<<dim3(12, KSPLIT), 256, 0, stream>>>(x, W_attn, ws + OFF_QKVP, 3 * DMODEL);
    // 2) reduce + bias; q -> ws (scaled), new k/v -> pools (paged write)
    qkv_reduce_scatter<<<192, 256, 0, stream>>>(ws + OFF_QKVP, b_attn, block_ids,
                                                ws + OFF_QW, kpool, vpool);
    // 3) flash-decode attention over the full prefix (f16 MFMA, 4-wave blocks)
    paged_attn<<<dim3(NHEAD, SPLITS), 256, 0, stream>>>(kpool, vpool, block_ids,
                                                        ws + OFF_QW, ws + OFF_ACC,
                                                        ws + OFF_M, ws + OFF_SE);
    // 4) combine splits
    combine<<<NHEAD * L_TOK, 256, 0, stream>>>(ws + OFF_ACC, ws + OFF_M, ws + OFF_SE,
                                               ws + OFF_ATTN);
    // 5) output projection (split-K partials)
    gemm_part<<<dim3(4, KSPLIT), 256, 0, stream>>>(ws + OFF_ATTN, W_proj, ws + OFF_PROJP, DMODEL);
    // 6) reduce + bias -> d_out
    proj_reduce<<<64, 256, 0, stream>>>(ws + OFF_PROJP, b_proj, out);
}